// Round 4
// baseline (619.274 us; speedup 1.0000x reference)
//
#include <hip/hip_runtime.h>
#include <math.h>

#define NB 16
#define NM 512
#define NT 64
#define NF 128
#define NH 128
#define PAD4 132   // padded f32 LDS row stride (132*4 = 528 B)

typedef short short8 __attribute__((ext_vector_type(8)));
typedef float floatx4 __attribute__((ext_vector_type(4)));

static __device__ __forceinline__ unsigned short f2b(float f) {
  union { float f; unsigned u; } v; v.f = f;
  unsigned r = v.u + 0x7fff + ((v.u >> 16) & 1);   // RNE
  return (unsigned short)(r >> 16);
}

// ---------- prep: WxFrag = bf16(W1b @ lin_w) packed in MFMA B-fragment lane order;
//            linT[f][i] = lin_w[i][f];  ubase[i] = mlp_b1[i] + W1b[i,:]@lin_b
__global__ __launch_bounds__(128) void prep_kernel(
    const float* __restrict__ lin_w, const float* __restrict__ mlp_w1,
    const float* __restrict__ lin_b, const float* __restrict__ mlp_b1,
    unsigned short* __restrict__ WxFrag, float* __restrict__ linT,
    float* __restrict__ ubase)
{
  const int tid = threadIdx.x;
  if (blockIdx.x < 128) {
    const int i = blockIdx.x;
    __shared__ float sw[128];
    __shared__ float rb[128];
    sw[tid] = mlp_w1[i * 256 + 128 + tid];   // W1b row i
    __syncthreads();
    float s = 0.f;
#pragma unroll 16
    for (int k = 0; k < 128; k++) s += sw[k] * lin_w[k * 128 + tid];
    // pack: value Wx[i][f] -> fragment position for pass1's bfr loads
    // row i = it*16+col ; f = kc*32 + quad*8 + jj ; lane = quad*16+col
    {
      const int it = i >> 4, col = i & 15;
      const int f = tid;
      const int kc = f >> 5, quad = (f >> 3) & 3, jj = f & 7;
      WxFrag[((it * 4 + kc) * 64 + quad * 16 + col) * 8 + jj] = f2b(s);
    }
    rb[tid] = sw[tid] * lin_b[tid];
    __syncthreads();
    if (tid == 0) {
      float s2 = 0.f;
      for (int k = 0; k < 128; k++) s2 += rb[k];
      ubase[i] = mlp_b1[i] + s2;
    }
  } else {
    const int f = blockIdx.x - 128;
    linT[f * 128 + tid] = lin_w[tid * 128 + f];
  }
}

// ---------- transpose helper: in[R][C] (row stride S) -> outT[C][R]
static __device__ __forceinline__ void tpose_tile(
    const float* __restrict__ in, float* __restrict__ outT,
    int R, int C, int S, int tileIdx)
{
  __shared__ float tile[32][33];
  const int tilesC = C >> 5;
  const int tr = tileIdx / tilesC, tc = tileIdx % tilesC;
  const int x = threadIdx.x & 31, y = threadIdx.x >> 5;   // 32x8
#pragma unroll
  for (int yy = y; yy < 32; yy += 8)
    tile[yy][x] = in[(size_t)(tr * 32 + yy) * S + tc * 32 + x];
  __syncthreads();
#pragma unroll
  for (int yy = y; yy < 32; yy += 8)
    outT[(size_t)(tc * 32 + yy) * R + tr * 32 + x] = tile[x][yy];
}

// grid: 48*4 + 16 = 208 blocks x 256 threads
__global__ __launch_bounds__(256) void tpose_kernel(
    const float* __restrict__ wih0, const float* __restrict__ whh0,
    const float* __restrict__ wih1, const float* __restrict__ whh1,
    const float* __restrict__ mlp_w1,
    float* __restrict__ wih0T, float* __restrict__ whh0T,
    float* __restrict__ wih1T, float* __restrict__ whh1T,
    float* __restrict__ W1aT)
{
  const int b = blockIdx.x;
  if (b < 48)        tpose_tile(wih0,   wih0T, 384, 128, 128, b);
  else if (b < 96)   tpose_tile(whh0,   whh0T, 384, 128, 128, b - 48);
  else if (b < 144)  tpose_tile(wih1,   wih1T, 384, 128, 128, b - 96);
  else if (b < 192)  tpose_tile(whh1,   whh1T, 384, 128, 128, b - 144);
  else               tpose_tile(mlp_w1, W1aT,  128, 128, 256, b - 192);  // first 128 cols
}

// ---------- u: u[bt][i] = ubase[i] + W1a[i,:]@h_target[bt]   (coalesced via W1aT)
__global__ __launch_bounds__(128) void u_kernel(
    const float* __restrict__ h_target, const float* __restrict__ W1aT,
    const float* __restrict__ ubase, float* __restrict__ u_out)
{
  const int bt = blockIdx.x, i = threadIdx.x;
  __shared__ float sht[128];
  sht[i] = h_target[bt * 128 + i];
  __syncthreads();
  float u = ubase[i];
#pragma unroll 16
  for (int k = 0; k < 128; k++) u += W1aT[k * 128 + i] * sht[k];
  u_out[bt * 128 + i] = u;
}

// ---------- pass1: per (bt, g): scores via MFMA -> lw -> weighted x partial sums
// X tile staged in LDS as f32 (aggregation in f32); bf16 A-fragments built on the fly.
// B-fragments read directly from global (L1-resident, wave-identical addresses).
__global__ __launch_bounds__(256, 4) void pass1_kernel(
    const float* __restrict__ X, const float* __restrict__ C,
    const float* __restrict__ dist,
    const unsigned short* __restrict__ WxFrag, const float* __restrict__ u_g,
    const float* __restrict__ mlp_w2, const float* __restrict__ mlp_b2,
    const float* __restrict__ lin2_w, const float* __restrict__ lin2_b,
    float* __restrict__ part, float* __restrict__ partls)
{
  const int blk = blockIdx.x;
  const int g = blk & 7, bt = blk >> 3;
  const int b = bt >> 6, t = bt & 63;
  const int tid = threadIdx.x;

  __shared__ float xs[64 * PAD4];      // 33792 B (f32 X tile)
  __shared__ float u_sh[128], w2_sh[128], lw_sh[64];
  __shared__ float red[2][128];
  __shared__ float red_ls;

  // x tile: 64 rows (m = g*64+row) x 128 f, f32 straight to LDS (padded rows)
  const float* Xbase = X + (((size_t)(b * NM + g * 64)) * NT + t) * NF;
#pragma unroll
  for (int p = 0; p < 8; p++) {
    int idx = p * 256 + tid;            // 0..2047 float4s
    int row = idx >> 5, c4 = idx & 31;
    float4 xv = *(const float4*)(Xbase + (size_t)row * NT * NF + c4 * 4);
    *(float4*)&xs[row * PAD4 + c4 * 4] = xv;
  }
  if (tid < 128) { u_sh[tid] = u_g[bt * 128 + tid]; w2_sh[tid] = mlp_w2[tid]; }
  __syncthreads();

  // MFMA: wave w computes S[w*16..+16, 0..128); A-fragments = bf16(f32 LDS)
  const int w = tid >> 6, lane = tid & 63;
  const int col = lane & 15, quad = lane >> 4;
  short8 afr[4];
#pragma unroll
  for (int kc = 0; kc < 4; kc++) {
    const float* src = &xs[(w * 16 + col) * PAD4 + kc * 32 + quad * 8];
    short8 a;
#pragma unroll
    for (int jv = 0; jv < 8; jv++) a[jv] = (short)f2b(src[jv]);
    afr[kc] = a;
  }
  floatx4 acc[8];
#pragma unroll
  for (int it = 0; it < 8; it++) acc[it] = {0.f, 0.f, 0.f, 0.f};
#pragma unroll
  for (int it = 0; it < 8; it++) {
#pragma unroll
    for (int kc = 0; kc < 4; kc++) {
      short8 bfr = *(const short8*)&WxFrag[((it * 4 + kc) * 64 + lane) * 8];
      acc[it] = __builtin_amdgcn_mfma_f32_16x16x32_bf16(afr[kc], bfr, acc[it], 0, 0, 0);
    }
  }

  // epilogue: v[m] = sum_i w2[i]*relu(S[m,i]+u[i]); reduce over col (low 4 lane bits)
  float w2l[8], ul[8];
#pragma unroll
  for (int it = 0; it < 8; it++) { w2l[it] = w2_sh[it * 16 + col]; ul[it] = u_sh[it * 16 + col]; }
  float vsum[4];
#pragma unroll
  for (int r = 0; r < 4; r++) {
    float v = 0.f;
#pragma unroll
    for (int it = 0; it < 8; it++) {
      float s = acc[it][r] + ul[it];
      v += w2l[it] * fmaxf(s, 0.f);
    }
    v += __shfl_xor(v, 1, 64);
    v += __shfl_xor(v, 2, 64);
    v += __shfl_xor(v, 4, 64);
    v += __shfl_xor(v, 8, 64);
    vsum[r] = v;
  }
  if (col == 0) {
    const float c0 = lin2_w[0], c1 = lin2_w[1], c2 = lin2_w[2];
    const float lb2 = lin2_b[0], mb2 = mlp_b2[0];
#pragma unroll
    for (int r = 0; r < 4; r++) {
      int ml = w * 16 + quad * 4 + r;
      int m = g * 64 + ml;
      float wmsg = vsum[r] + mb2;
      lw_sh[ml] = C[((size_t)b * NM + m) * NT + t] * c0 + dist[m] * c1 + wmsg * c2 + lb2;
    }
  }
  __syncthreads();

  // weighted sum over this m-chunk — f32 X (no bf16 quantization on h_agg path)
  const int f = tid & 127, half = tid >> 7;
  float xa = 0.f;
#pragma unroll 8
  for (int mm = half * 32; mm < half * 32 + 32; mm++)
    xa += lw_sh[mm] * xs[mm * PAD4 + f];
  red[half][f] = xa;
  if (tid < 64) {                       // wave-parallel sum of lw_sh
    float v = lw_sh[tid];
    v += __shfl_xor(v, 1, 64);
    v += __shfl_xor(v, 2, 64);
    v += __shfl_xor(v, 4, 64);
    v += __shfl_xor(v, 8, 64);
    v += __shfl_xor(v, 16, 64);
    v += __shfl_xor(v, 32, 64);
    if (tid == 0) red_ls = v;
  }
  __syncthreads();
  if (tid < 128) part[(size_t)blk * 128 + tid] = red[0][tid] + red[1][tid];
  if (tid == 128) partls[blk] = red_ls;
}

// ---------- reduce: xagg -> h_agg -> gi0   (coalesced via wih0T)
__global__ __launch_bounds__(384) void reduce_kernel(
    const float* __restrict__ part, const float* __restrict__ partls,
    const float* __restrict__ linT, const float* __restrict__ lin_b,
    const float* __restrict__ wih0T, const float* __restrict__ bih0,
    float* __restrict__ gi0)
{
  const int bt = blockIdx.x, j = threadIdx.x;
  __shared__ float sxa[128], shh[128];
  __shared__ float sls;
  if (j < 128) {
    float s = 0.f;
#pragma unroll
    for (int g2 = 0; g2 < 8; g2++) s += part[((size_t)bt * 8 + g2) * 128 + j];
    sxa[j] = s;
  }
  if (j == 128) {
    float s = 0.f;
#pragma unroll
    for (int g2 = 0; g2 < 8; g2++) s += partls[bt * 8 + g2];
    sls = s;
  }
  __syncthreads();
  if (j < 128) {
    float hv = sls * lin_b[j];
#pragma unroll 8
    for (int f2 = 0; f2 < 128; f2++) hv += linT[f2 * 128 + j] * sxa[f2];
    shh[j] = hv;
  }
  __syncthreads();
  float gacc = bih0[j];
#pragma unroll 16
  for (int k = 0; k < 128; k++) gacc += wih0T[k * 384 + j] * shh[k];
  gi0[(size_t)bt * 384 + j] = gacc;
}

// ---------- gi for layer 1  (coalesced via wihT)
__global__ __launch_bounds__(384, 2) void gi_kernel(
    const float* __restrict__ xin, const float* __restrict__ wihT,
    const float* __restrict__ bih, float* __restrict__ gi)
{
  __shared__ __align__(16) float xr[128];
  const int bt = blockIdx.x, j = threadIdx.x;
  if (j < 128) xr[j] = xin[bt * 128 + j];
  __syncthreads();
  float a0 = 0.f, a1 = 0.f, a2 = 0.f, a3 = 0.f;
#pragma unroll 8
  for (int k = 0; k < 128; k += 4) {
    a0 += wihT[(k    ) * 384 + j] * xr[k];
    a1 += wihT[(k + 1) * 384 + j] * xr[k + 1];
    a2 += wihT[(k + 2) * 384 + j] * xr[k + 2];
    a3 += wihT[(k + 3) * 384 + j] * xr[k + 3];
  }
  gi[(size_t)bt * 384 + j] = (a0 + a1) + (a2 + a3) + bih[j];
}

// ---------- GRU recurrence: gi preloaded to LDS; precise transcendentals
__global__ __launch_bounds__(384, 1) void gru_layer_kernel(
    const float* __restrict__ gi, const float* __restrict__ whhT,
    const float* __restrict__ bhh, float* __restrict__ out)
{
  const int b = blockIdx.x, j = threadIdx.x;
  __shared__ float sgi[64 * 384];   // 96 KB
  __shared__ float hs[128], ghs[384];

  const float4* gsrc = (const float4*)(gi + (size_t)b * 64 * 384);
  float4* gdst = (float4*)sgi;
#pragma unroll
  for (int p = 0; p < 16; p++) gdst[p * 384 + j] = gsrc[p * 384 + j];

  float wreg[128];
#pragma unroll
  for (int k = 0; k < 128; k++) wreg[k] = whhT[k * 384 + j];
  const float bh = bhh[j];
  if (j < 128) hs[j] = 0.f;
  __syncthreads();

  for (int t = 0; t < NT; t++) {
    float a0 = 0.f, a1 = 0.f, a2 = 0.f, a3 = 0.f;
    const float4* h4 = (const float4*)hs;
#pragma unroll
    for (int k = 0; k < 32; k++) {
      float4 hv = h4[k];
      a0 += wreg[4 * k]     * hv.x;
      a1 += wreg[4 * k + 1] * hv.y;
      a2 += wreg[4 * k + 2] * hv.z;
      a3 += wreg[4 * k + 3] * hv.w;
    }
    ghs[j] = (a0 + a1) + (a2 + a3) + bh;
    __syncthreads();
    if (j < 128) {
      const float* gt = &sgi[t * 384];
      const float hprev = hs[j];
      const float r = 1.f / (1.f + expf(-(gt[j] + ghs[j])));
      const float z = 1.f / (1.f + expf(-(gt[128 + j] + ghs[128 + j])));
      const float n = tanhf(gt[256 + j] + r * ghs[256 + j]);
      const float hnew = (1.f - z) * n + z * hprev;
      hs[j] = hnew;
      out[((size_t)b * NT + t) * 128 + j] = hnew;
    }
    __syncthreads();
  }
}

extern "C" void kernel_launch(void* const* d_in, const int* in_sizes, int n_in,
                              void* d_out, int out_size, void* d_ws, size_t ws_size,
                              hipStream_t stream)
{
  const float* X        = (const float*)d_in[0];
  const float* C        = (const float*)d_in[1];
  const float* h_target = (const float*)d_in[2];
  const float* distance = (const float*)d_in[3];
  const float* lin_w    = (const float*)d_in[4];
  const float* lin_b    = (const float*)d_in[5];
  const float* mlp_w1   = (const float*)d_in[6];
  const float* mlp_b1   = (const float*)d_in[7];
  const float* mlp_w2   = (const float*)d_in[8];
  const float* mlp_b2   = (const float*)d_in[9];
  const float* lin2_w   = (const float*)d_in[10];
  const float* lin2_b   = (const float*)d_in[11];
  const float* wih0     = (const float*)d_in[12];
  const float* whh0     = (const float*)d_in[13];
  const float* bih0     = (const float*)d_in[14];
  const float* bhh0     = (const float*)d_in[15];
  const float* wih1     = (const float*)d_in[16];
  const float* whh1     = (const float*)d_in[17];
  const float* bih1     = (const float*)d_in[18];
  const float* bhh1     = (const float*)d_in[19];
  float* out = (float*)d_out;

  float* ws = (float*)d_ws;
  unsigned short* WxFrag = (unsigned short*)ws;      //  16384 bf16  (= 8192 floats)
  float* linT   = ws + 8192;                         //  16384
  float* u_buf  = ws + 24576;                        // 131072
  float* part   = ws + 155648;                       // 8192*128 = 1048576
  float* partls = ws + 1204224;                      //   8192
  float* gi     = ws + 1212416;                      // 393216
  float* out0   = ws + 1605632;                      // 131072
  float* W1aT   = ws + 1736704;                      //  16384
  float* wih0T  = ws + 1753088;                      //  49152
  float* whh0T  = ws + 1802240;                      //  49152
  float* wih1T  = ws + 1851392;                      //  49152
  float* whh1T  = ws + 1900544;                      //  49152
  float* ubase  = ws + 1949696;                      //    128   (total ~7.8 MB)

  prep_kernel<<<256, 128, 0, stream>>>(lin_w, mlp_w1, lin_b, mlp_b1, WxFrag, linT, ubase);
  tpose_kernel<<<208, 256, 0, stream>>>(wih0, whh0, wih1, whh1, mlp_w1,
      wih0T, whh0T, wih1T, whh1T, W1aT);
  u_kernel<<<NB * NT, 128, 0, stream>>>(h_target, W1aT, ubase, u_buf);
  pass1_kernel<<<NB * NT * 8, 256, 0, stream>>>(X, C, distance, WxFrag, u_buf,
      mlp_w2, mlp_b2, lin2_w, lin2_b, part, partls);
  reduce_kernel<<<NB * NT, 384, 0, stream>>>(part, partls, linT, lin_b, wih0T, bih0, gi);
  gru_layer_kernel<<<NB, 384, 0, stream>>>(gi, whh0T, bhh0, out0);
  gi_kernel<<<NB * NT, 384, 0, stream>>>(out0, wih1T, bih1, gi);
  gru_layer_kernel<<<NB, 384, 0, stream>>>(gi, whh1T, bhh1, out);
}

// Round 5
// 559.556 us; speedup vs baseline: 1.1067x; 1.1067x over previous
//
#include <hip/hip_runtime.h>
#include <math.h>

#define NB 16
#define NM 512
#define NT 64
#define NF 128
#define NH 128
#define PAD4 132   // padded f32 LDS row stride (132*4 = 528 B)

typedef short short8 __attribute__((ext_vector_type(8)));
typedef float floatx4 __attribute__((ext_vector_type(4)));
typedef float f4 __attribute__((ext_vector_type(4)));

static __device__ __forceinline__ unsigned short f2b(float f) {
  union { float f; unsigned u; } v; v.f = f;
  unsigned r = v.u + 0x7fff + ((v.u >> 16) & 1);   // RNE
  return (unsigned short)(r >> 16);
}

// ---------- transpose helper: in[R][C] (row stride S) -> outT[C][R]
static __device__ __forceinline__ void tpose_tile(
    const float* __restrict__ in, float* __restrict__ outT,
    int R, int C, int S, int tileIdx)
{
  __shared__ float tile[32][33];
  const int tilesC = C >> 5;
  const int tr = tileIdx / tilesC, tc = tileIdx % tilesC;
  const int x = threadIdx.x & 31, y = threadIdx.x >> 5;   // 32x8
#pragma unroll
  for (int yy = y; yy < 32; yy += 8)
    tile[yy][x] = in[(size_t)(tr * 32 + yy) * S + tc * 32 + x];
  __syncthreads();
#pragma unroll
  for (int yy = y; yy < 32; yy += 8)
    outT[(size_t)(tc * 32 + yy) * R + tr * 32 + x] = tile[x][yy];
}

// ---------- setup: merged prep + all transposes. grid 352 x 256
// blocks 0..127:   WxFrag row i (MFMA B-fragment order) + ubase[i]
// blocks 128..351: weight transposes (wih0,whh0,wih1,whh1,W1a,lin_w)
__global__ __launch_bounds__(256) void setup_kernel(
    const float* __restrict__ lin_w, const float* __restrict__ mlp_w1,
    const float* __restrict__ lin_b, const float* __restrict__ mlp_b1,
    const float* __restrict__ wih0, const float* __restrict__ whh0,
    const float* __restrict__ wih1, const float* __restrict__ whh1,
    unsigned short* __restrict__ WxFrag, float* __restrict__ linT,
    float* __restrict__ ubase,
    float* __restrict__ wih0T, float* __restrict__ whh0T,
    float* __restrict__ wih1T, float* __restrict__ whh1T,
    float* __restrict__ W1aT)
{
  const int blk = blockIdx.x;
  const int tid = threadIdx.x;
  if (blk < 128) {
    const int i = blk;
    __shared__ float sw[128];
    __shared__ float rb[128];
    if (tid < 128) sw[tid] = mlp_w1[i * 256 + 128 + tid];   // W1b row i
    __syncthreads();
    if (tid < 128) {
      float s = 0.f;
#pragma unroll 16
      for (int k = 0; k < 128; k++) s += sw[k] * lin_w[k * 128 + tid];
      // pack: Wx[i][f] -> B-fragment slot. row i = it*16+col ; f = kc*32+quad*8+jj
      const int it = i >> 4, col = i & 15;
      const int f = tid;
      const int kc = f >> 5, quad = (f >> 3) & 3, jj = f & 7;
      WxFrag[((it * 4 + kc) * 64 + quad * 16 + col) * 8 + jj] = f2b(s);
      rb[tid] = sw[tid] * lin_b[tid];
    }
    __syncthreads();
    if (tid == 0) {
      float s2 = 0.f;
      for (int k = 0; k < 128; k++) s2 += rb[k];
      ubase[i] = mlp_b1[i] + s2;
    }
  } else {
    const int c = blk - 128;
    if (c < 48)        tpose_tile(wih0,   wih0T, 384, 128, 128, c);
    else if (c < 96)   tpose_tile(whh0,   whh0T, 384, 128, 128, c - 48);
    else if (c < 144)  tpose_tile(wih1,   wih1T, 384, 128, 128, c - 96);
    else if (c < 192)  tpose_tile(whh1,   whh1T, 384, 128, 128, c - 144);
    else if (c < 208)  tpose_tile(mlp_w1, W1aT,  128, 128, 256, c - 192);  // first 128 cols
    else               tpose_tile(lin_w,  linT,  128, 128, 128, c - 208);
  }
}

// ---------- u: u[bt][i] = ubase[i] + W1a[i,:]@h_target[bt]   (coalesced via W1aT)
__global__ __launch_bounds__(128) void u_kernel(
    const float* __restrict__ h_target, const float* __restrict__ W1aT,
    const float* __restrict__ ubase, float* __restrict__ u_out)
{
  const int bt = blockIdx.x, i = threadIdx.x;
  __shared__ float sht[128];
  sht[i] = h_target[bt * 128 + i];
  __syncthreads();
  float u = ubase[i];
#pragma unroll 16
  for (int k = 0; k < 128; k++) u += W1aT[k * 128 + i] * sht[k];
  u_out[bt * 128 + i] = u;
}

// ---------- pass1: per (bt, g): scores via MFMA -> lw -> weighted x partial sums
// X staged f32 in LDS (nontemporal loads: protect WxFrag L1 residency);
// B-fragments read from global (wave-identical addresses, L1-resident).
__global__ __launch_bounds__(256, 4) void pass1_kernel(
    const float* __restrict__ X, const float* __restrict__ C,
    const float* __restrict__ dist,
    const unsigned short* __restrict__ WxFrag, const float* __restrict__ u_g,
    const float* __restrict__ mlp_w2, const float* __restrict__ mlp_b2,
    const float* __restrict__ lin2_w, const float* __restrict__ lin2_b,
    float* __restrict__ part, float* __restrict__ partls)
{
  const int blk = blockIdx.x;
  const int g = blk & 7, bt = blk >> 3;
  const int b = bt >> 6, t = bt & 63;
  const int tid = threadIdx.x;

  __shared__ float xs[64 * PAD4];      // 33792 B (f32 X tile)
  __shared__ float u_sh[128], w2_sh[128], lw_sh[64];
  __shared__ float red[2][128];
  __shared__ float red_ls;

  // x tile: 64 rows (m = g*64+row) x 128 f, f32 straight to LDS (padded rows)
  const float* Xbase = X + (((size_t)(b * NM + g * 64)) * NT + t) * NF;
#pragma unroll
  for (int p = 0; p < 8; p++) {
    int idx = p * 256 + tid;            // 0..2047 float4s
    int row = idx >> 5, c4 = idx & 31;
    f4 xv = __builtin_nontemporal_load((const f4*)(Xbase + (size_t)row * NT * NF + c4 * 4));
    *(f4*)&xs[row * PAD4 + c4 * 4] = xv;
  }
  if (tid < 128) { u_sh[tid] = u_g[bt * 128 + tid]; w2_sh[tid] = mlp_w2[tid]; }
  __syncthreads();

  // MFMA: wave w computes S[w*16..+16, 0..128); A-fragments = bf16(f32 LDS)
  const int w = tid >> 6, lane = tid & 63;
  const int col = lane & 15, quad = lane >> 4;
  short8 afr[4];
#pragma unroll
  for (int kc = 0; kc < 4; kc++) {
    const float* src = &xs[(w * 16 + col) * PAD4 + kc * 32 + quad * 8];
    short8 a;
#pragma unroll
    for (int jv = 0; jv < 8; jv++) a[jv] = (short)f2b(src[jv]);
    afr[kc] = a;
  }
  floatx4 acc[8];
#pragma unroll
  for (int it = 0; it < 8; it++) acc[it] = {0.f, 0.f, 0.f, 0.f};
#pragma unroll
  for (int it = 0; it < 8; it++) {
#pragma unroll
    for (int kc = 0; kc < 4; kc++) {
      short8 bfr = *(const short8*)&WxFrag[((it * 4 + kc) * 64 + lane) * 8];
      acc[it] = __builtin_amdgcn_mfma_f32_16x16x32_bf16(afr[kc], bfr, acc[it], 0, 0, 0);
    }
  }

  // epilogue: v[m] = sum_i w2[i]*relu(S[m,i]+u[i]); reduce over col (low 4 lane bits)
  float w2l[8], ul[8];
#pragma unroll
  for (int it = 0; it < 8; it++) { w2l[it] = w2_sh[it * 16 + col]; ul[it] = u_sh[it * 16 + col]; }
  float vsum[4];
#pragma unroll
  for (int r = 0; r < 4; r++) {
    float v = 0.f;
#pragma unroll
    for (int it = 0; it < 8; it++) {
      float s = acc[it][r] + ul[it];
      v += w2l[it] * fmaxf(s, 0.f);
    }
    v += __shfl_xor(v, 1, 64);
    v += __shfl_xor(v, 2, 64);
    v += __shfl_xor(v, 4, 64);
    v += __shfl_xor(v, 8, 64);
    vsum[r] = v;
  }
  if (col == 0) {
    const float c0 = lin2_w[0], c1 = lin2_w[1], c2 = lin2_w[2];
    const float lb2 = lin2_b[0], mb2 = mlp_b2[0];
#pragma unroll
    for (int r = 0; r < 4; r++) {
      int ml = w * 16 + quad * 4 + r;
      int m = g * 64 + ml;
      float wmsg = vsum[r] + mb2;
      lw_sh[ml] = C[((size_t)b * NM + m) * NT + t] * c0 + dist[m] * c1 + wmsg * c2 + lb2;
    }
  }
  __syncthreads();

  // weighted sum over this m-chunk — f32 X (no bf16 quantization on h_agg path)
  const int f = tid & 127, half = tid >> 7;
  float xa = 0.f;
#pragma unroll 8
  for (int mm = half * 32; mm < half * 32 + 32; mm++)
    xa += lw_sh[mm] * xs[mm * PAD4 + f];
  red[half][f] = xa;
  if (tid < 64) {                       // wave-parallel sum of lw_sh
    float v = lw_sh[tid];
    v += __shfl_xor(v, 1, 64);
    v += __shfl_xor(v, 2, 64);
    v += __shfl_xor(v, 4, 64);
    v += __shfl_xor(v, 8, 64);
    v += __shfl_xor(v, 16, 64);
    v += __shfl_xor(v, 32, 64);
    if (tid == 0) red_ls = v;
  }
  __syncthreads();
  if (tid < 128) __builtin_nontemporal_store(red[0][tid] + red[1][tid],
                                             &part[(size_t)blk * 128 + tid]);
  if (tid == 128) partls[blk] = red_ls;
}

// ---------- reduce: xagg -> h_agg -> gi0   (coalesced via wih0T)
__global__ __launch_bounds__(384) void reduce_kernel(
    const float* __restrict__ part, const float* __restrict__ partls,
    const float* __restrict__ linT, const float* __restrict__ lin_b,
    const float* __restrict__ wih0T, const float* __restrict__ bih0,
    float* __restrict__ gi0)
{
  const int bt = blockIdx.x, j = threadIdx.x;
  __shared__ float sxa[128], shh[128];
  __shared__ float sls;
  if (j < 128) {
    float s = 0.f;
#pragma unroll
    for (int g2 = 0; g2 < 8; g2++)
      s += __builtin_nontemporal_load(&part[((size_t)bt * 8 + g2) * 128 + j]);
    sxa[j] = s;
  }
  if (j == 128) {
    float s = 0.f;
#pragma unroll
    for (int g2 = 0; g2 < 8; g2++) s += partls[bt * 8 + g2];
    sls = s;
  }
  __syncthreads();
  if (j < 128) {
    float hv = sls * lin_b[j];
#pragma unroll 8
    for (int f2 = 0; f2 < 128; f2++) hv += linT[f2 * 128 + j] * sxa[f2];
    shh[j] = hv;
  }
  __syncthreads();
  float gacc = bih0[j];
#pragma unroll 16
  for (int k = 0; k < 128; k++) gacc += wih0T[k * 384 + j] * shh[k];
  gi0[(size_t)bt * 384 + j] = gacc;
}

// ---------- gi for layer 1  (coalesced via wihT)
__global__ __launch_bounds__(384, 2) void gi_kernel(
    const float* __restrict__ xin, const float* __restrict__ wihT,
    const float* __restrict__ bih, float* __restrict__ gi)
{
  __shared__ __align__(16) float xr[128];
  const int bt = blockIdx.x, j = threadIdx.x;
  if (j < 128) xr[j] = xin[bt * 128 + j];
  __syncthreads();
  float a0 = 0.f, a1 = 0.f, a2 = 0.f, a3 = 0.f;
#pragma unroll 8
  for (int k = 0; k < 128; k += 4) {
    a0 += wihT[(k    ) * 384 + j] * xr[k];
    a1 += wihT[(k + 1) * 384 + j] * xr[k + 1];
    a2 += wihT[(k + 2) * 384 + j] * xr[k + 2];
    a3 += wihT[(k + 3) * 384 + j] * xr[k + 3];
  }
  gi[(size_t)bt * 384 + j] = (a0 + a1) + (a2 + a3) + bih[j];
}

// ---------- GRU recurrence: 768 threads, K-split matvec (2x64), precise transcendentals
__global__ __launch_bounds__(768) void gru_layer_kernel(
    const float* __restrict__ gi, const float* __restrict__ whhT,
    const float* __restrict__ bhh, float* __restrict__ out)
{
  const int b = blockIdx.x, tid = threadIdx.x;
  const int kh = (tid >= 384) ? 1 : 0;
  const int j  = tid - kh * 384;

  __shared__ float sgi[64 * 384];   // 96 KB
  __shared__ float hs[128];
  __shared__ float pg[2][384];

  // preload gi: 6144 float4 over 768 threads = 8 rounds
  const float4* gsrc = (const float4*)(gi + (size_t)b * 64 * 384);
  float4* gdst = (float4*)sgi;
#pragma unroll
  for (int p = 0; p < 8; p++) gdst[p * 768 + tid] = gsrc[p * 768 + tid];

  // each thread holds half a whh row (K-split): wreg[k] = whh[j][kh*64+k]
  float wreg[64];
#pragma unroll
  for (int k = 0; k < 64; k++) wreg[k] = whhT[(kh * 64 + k) * 384 + j];
  const float bh = (kh == 0) ? bhh[j] : 0.f;
  if (tid < 128) hs[tid] = 0.f;
  __syncthreads();

  for (int t = 0; t < NT; t++) {
    const float4* h4 = ((const float4*)hs) + kh * 16;
    float a0 = 0.f, a1 = 0.f, a2 = 0.f, a3 = 0.f;
#pragma unroll
    for (int k = 0; k < 16; k++) {
      float4 hv = h4[k];
      a0 += wreg[4 * k]     * hv.x;
      a1 += wreg[4 * k + 1] * hv.y;
      a2 += wreg[4 * k + 2] * hv.z;
      a3 += wreg[4 * k + 3] * hv.w;
    }
    pg[kh][j] = (a0 + a1) + (a2 + a3) + bh;
    __syncthreads();
    if (tid < 128) {
      const float* gt = &sgi[t * 384];
      const float ghr = pg[0][tid]       + pg[1][tid];
      const float ghz = pg[0][tid + 128] + pg[1][tid + 128];
      const float ghn = pg[0][tid + 256] + pg[1][tid + 256];
      const float hprev = hs[tid];
      const float r = 1.f / (1.f + expf(-(gt[tid] + ghr)));
      const float z = 1.f / (1.f + expf(-(gt[tid + 128] + ghz)));
      const float n = tanhf(gt[tid + 256] + r * ghn);
      const float hnew = (1.f - z) * n + z * hprev;
      hs[tid] = hnew;
      out[((size_t)b * NT + t) * 128 + tid] = hnew;
    }
    __syncthreads();
  }
}

extern "C" void kernel_launch(void* const* d_in, const int* in_sizes, int n_in,
                              void* d_out, int out_size, void* d_ws, size_t ws_size,
                              hipStream_t stream)
{
  const float* X        = (const float*)d_in[0];
  const float* C        = (const float*)d_in[1];
  const float* h_target = (const float*)d_in[2];
  const float* distance = (const float*)d_in[3];
  const float* lin_w    = (const float*)d_in[4];
  const float* lin_b    = (const float*)d_in[5];
  const float* mlp_w1   = (const float*)d_in[6];
  const float* mlp_b1   = (const float*)d_in[7];
  const float* mlp_w2   = (const float*)d_in[8];
  const float* mlp_b2   = (const float*)d_in[9];
  const float* lin2_w   = (const float*)d_in[10];
  const float* lin2_b   = (const float*)d_in[11];
  const float* wih0     = (const float*)d_in[12];
  const float* whh0     = (const float*)d_in[13];
  const float* bih0     = (const float*)d_in[14];
  const float* bhh0     = (const float*)d_in[15];
  const float* wih1     = (const float*)d_in[16];
  const float* whh1     = (const float*)d_in[17];
  const float* bih1     = (const float*)d_in[18];
  const float* bhh1     = (const float*)d_in[19];
  float* out = (float*)d_out;

  float* ws = (float*)d_ws;
  unsigned short* WxFrag = (unsigned short*)ws;      //  16384 bf16  (= 8192 floats)
  float* linT   = ws + 8192;                         //  16384
  float* u_buf  = ws + 24576;                        // 131072
  float* part   = ws + 155648;                       // 8192*128 = 1048576
  float* partls = ws + 1204224;                      //   8192
  float* gi     = ws + 1212416;                      // 393216
  float* out0   = ws + 1605632;                      // 131072
  float* W1aT   = ws + 1736704;                      //  16384
  float* wih0T  = ws + 1753088;                      //  49152
  float* whh0T  = ws + 1802240;                      //  49152
  float* wih1T  = ws + 1851392;                      //  49152
  float* whh1T  = ws + 1900544;                      //  49152
  float* ubase  = ws + 1949696;                      //    128   (total ~7.8 MB)

  setup_kernel<<<352, 256, 0, stream>>>(lin_w, mlp_w1, lin_b, mlp_b1,
      wih0, whh0, wih1, whh1,
      WxFrag, linT, ubase, wih0T, whh0T, wih1T, whh1T, W1aT);
  u_kernel<<<NB * NT, 128, 0, stream>>>(h_target, W1aT, ubase, u_buf);
  pass1_kernel<<<NB * NT * 8, 256, 0, stream>>>(X, C, distance, WxFrag, u_buf,
      mlp_w2, mlp_b2, lin2_w, lin2_b, part, partls);
  reduce_kernel<<<NB * NT, 384, 0, stream>>>(part, partls, linT, lin_b, wih0T, bih0, gi);
  gru_layer_kernel<<<NB, 768, 0, stream>>>(gi, whh0T, bhh0, out0);
  gi_kernel<<<NB * NT, 384, 0, stream>>>(out0, wih1T, bih1, gi);
  gru_layer_kernel<<<NB, 768, 0, stream>>>(gi, whh1T, bhh1, out);
}

// Round 6
// 546.355 us; speedup vs baseline: 1.1335x; 1.0242x over previous
//
#include <hip/hip_runtime.h>
#include <math.h>

#define NB 16
#define NM 512
#define NT 64
#define NF 128
#define NH 128
#define PAD4 132   // padded f32 LDS row stride (132*4 = 528 B)

typedef short short8 __attribute__((ext_vector_type(8)));
typedef float floatx4 __attribute__((ext_vector_type(4)));
typedef float f4 __attribute__((ext_vector_type(4)));

static __device__ __forceinline__ unsigned short f2b(float f) {
  union { float f; unsigned u; } v; v.f = f;
  unsigned r = v.u + 0x7fff + ((v.u >> 16) & 1);   // RNE
  return (unsigned short)(r >> 16);
}

// ---------- transpose helper: in[R][C] (row stride S) -> outT[C][R]
static __device__ __forceinline__ void tpose_tile(
    const float* __restrict__ in, float* __restrict__ outT,
    int R, int C, int S, int tileIdx)
{
  __shared__ float tile[32][33];
  const int tilesC = C >> 5;
  const int tr = tileIdx / tilesC, tc = tileIdx % tilesC;
  const int x = threadIdx.x & 31, y = threadIdx.x >> 5;   // 32x8
#pragma unroll
  for (int yy = y; yy < 32; yy += 8)
    tile[yy][x] = in[(size_t)(tr * 32 + yy) * S + tc * 32 + x];
  __syncthreads();
#pragma unroll
  for (int yy = y; yy < 32; yy += 8)
    outT[(size_t)(tc * 32 + yy) * R + tr * 32 + x] = tile[x][yy];
}

// ---------- setup: merged prep + all transposes. grid 352 x 256
__global__ __launch_bounds__(256) void setup_kernel(
    const float* __restrict__ lin_w, const float* __restrict__ mlp_w1,
    const float* __restrict__ lin_b, const float* __restrict__ mlp_b1,
    const float* __restrict__ wih0, const float* __restrict__ whh0,
    const float* __restrict__ wih1, const float* __restrict__ whh1,
    unsigned short* __restrict__ WxFrag, float* __restrict__ linT,
    float* __restrict__ ubase,
    float* __restrict__ wih0T, float* __restrict__ whh0T,
    float* __restrict__ wih1T, float* __restrict__ whh1T,
    float* __restrict__ W1aT)
{
  const int blk = blockIdx.x;
  const int tid = threadIdx.x;
  if (blk < 128) {
    const int i = blk;
    __shared__ float sw[128];
    __shared__ float rb[128];
    if (tid < 128) sw[tid] = mlp_w1[i * 256 + 128 + tid];   // W1b row i
    __syncthreads();
    if (tid < 128) {
      float s = 0.f;
#pragma unroll 16
      for (int k = 0; k < 128; k++) s += sw[k] * lin_w[k * 128 + tid];
      // pack: Wx[i][f] -> B-fragment slot. row i = it*16+col ; f = kc*32+quad*8+jj
      const int it = i >> 4, col = i & 15;
      const int f = tid;
      const int kc = f >> 5, quad = (f >> 3) & 3, jj = f & 7;
      WxFrag[((it * 4 + kc) * 64 + quad * 16 + col) * 8 + jj] = f2b(s);
      rb[tid] = sw[tid] * lin_b[tid];
    }
    __syncthreads();
    if (tid == 0) {
      float s2 = 0.f;
      for (int k = 0; k < 128; k++) s2 += rb[k];
      ubase[i] = mlp_b1[i] + s2;
    }
  } else {
    const int c = blk - 128;
    if (c < 48)        tpose_tile(wih0,   wih0T, 384, 128, 128, c);
    else if (c < 96)   tpose_tile(whh0,   whh0T, 384, 128, 128, c - 48);
    else if (c < 144)  tpose_tile(wih1,   wih1T, 384, 128, 128, c - 96);
    else if (c < 192)  tpose_tile(whh1,   whh1T, 384, 128, 128, c - 144);
    else if (c < 208)  tpose_tile(mlp_w1, W1aT,  128, 128, 256, c - 192);  // first 128 cols
    else               tpose_tile(lin_w,  linT,  128, 128, 128, c - 208);
  }
}

// ---------- u: u[bt][i] = ubase[i] + W1a[i,:]@h_target[bt]   (coalesced via W1aT)
__global__ __launch_bounds__(128) void u_kernel(
    const float* __restrict__ h_target, const float* __restrict__ W1aT,
    const float* __restrict__ ubase, float* __restrict__ u_out)
{
  const int bt = blockIdx.x, i = threadIdx.x;
  __shared__ float sht[128];
  sht[i] = h_target[bt * 128 + i];
  __syncthreads();
  float u = ubase[i];
#pragma unroll 16
  for (int k = 0; k < 128; k++) u += W1aT[k * 128 + i] * sht[k];
  u_out[bt * 128 + i] = u;
}

// ---------- pass1: per (bt, g): scores via MFMA -> lw -> weighted x partial sums
// X staged f32 in LDS (nontemporal loads); B-fragments read from global (L1-resident).
__global__ __launch_bounds__(256, 4) void pass1_kernel(
    const float* __restrict__ X, const float* __restrict__ C,
    const float* __restrict__ dist,
    const unsigned short* __restrict__ WxFrag, const float* __restrict__ u_g,
    const float* __restrict__ mlp_w2, const float* __restrict__ mlp_b2,
    const float* __restrict__ lin2_w, const float* __restrict__ lin2_b,
    float* __restrict__ part, float* __restrict__ partls)
{
  const int blk = blockIdx.x;
  const int g = blk & 7, bt = blk >> 3;
  const int b = bt >> 6, t = bt & 63;
  const int tid = threadIdx.x;

  __shared__ float xs[64 * PAD4];      // 33792 B (f32 X tile)
  __shared__ float u_sh[128], w2_sh[128], lw_sh[64];
  __shared__ float red[2][128];
  __shared__ float red_ls;

  // x tile: 64 rows (m = g*64+row) x 128 f, f32 straight to LDS (padded rows)
  const float* Xbase = X + (((size_t)(b * NM + g * 64)) * NT + t) * NF;
#pragma unroll
  for (int p = 0; p < 8; p++) {
    int idx = p * 256 + tid;            // 0..2047 float4s
    int row = idx >> 5, c4 = idx & 31;
    f4 xv = __builtin_nontemporal_load((const f4*)(Xbase + (size_t)row * NT * NF + c4 * 4));
    *(f4*)&xs[row * PAD4 + c4 * 4] = xv;
  }
  if (tid < 128) { u_sh[tid] = u_g[bt * 128 + tid]; w2_sh[tid] = mlp_w2[tid]; }
  __syncthreads();

  // MFMA: wave w computes S[w*16..+16, 0..128); A-fragments = bf16(f32 LDS)
  const int w = tid >> 6, lane = tid & 63;
  const int col = lane & 15, quad = lane >> 4;
  short8 afr[4];
#pragma unroll
  for (int kc = 0; kc < 4; kc++) {
    const f4* src = (const f4*)&xs[(w * 16 + col) * PAD4 + kc * 32 + quad * 8];
    f4 x0 = src[0], x1 = src[1];
    short8 a;
    a[0] = (short)f2b(x0[0]); a[1] = (short)f2b(x0[1]);
    a[2] = (short)f2b(x0[2]); a[3] = (short)f2b(x0[3]);
    a[4] = (short)f2b(x1[0]); a[5] = (short)f2b(x1[1]);
    a[6] = (short)f2b(x1[2]); a[7] = (short)f2b(x1[3]);
    afr[kc] = a;
  }
  floatx4 acc[8];
#pragma unroll
  for (int it = 0; it < 8; it++) acc[it] = {0.f, 0.f, 0.f, 0.f};
#pragma unroll
  for (int it = 0; it < 8; it++) {
#pragma unroll
    for (int kc = 0; kc < 4; kc++) {
      short8 bfr = *(const short8*)&WxFrag[((it * 4 + kc) * 64 + lane) * 8];
      acc[it] = __builtin_amdgcn_mfma_f32_16x16x32_bf16(afr[kc], bfr, acc[it], 0, 0, 0);
    }
  }

  // epilogue: v[m] = sum_i w2[i]*relu(S[m,i]+u[i]); reduce over col (low 4 lane bits)
  float w2l[8], ul[8];
#pragma unroll
  for (int it = 0; it < 8; it++) { w2l[it] = w2_sh[it * 16 + col]; ul[it] = u_sh[it * 16 + col]; }
  float vsum[4];
#pragma unroll
  for (int r = 0; r < 4; r++) {
    float v = 0.f;
#pragma unroll
    for (int it = 0; it < 8; it++) {
      float s = acc[it][r] + ul[it];
      v += w2l[it] * fmaxf(s, 0.f);
    }
    v += __shfl_xor(v, 1, 64);
    v += __shfl_xor(v, 2, 64);
    v += __shfl_xor(v, 4, 64);
    v += __shfl_xor(v, 8, 64);
    vsum[r] = v;
  }
  if (col == 0) {
    const float c0 = lin2_w[0], c1 = lin2_w[1], c2 = lin2_w[2];
    const float lb2 = lin2_b[0], mb2 = mlp_b2[0];
#pragma unroll
    for (int r = 0; r < 4; r++) {
      int ml = w * 16 + quad * 4 + r;
      int m = g * 64 + ml;
      float wmsg = vsum[r] + mb2;
      lw_sh[ml] = C[((size_t)b * NM + m) * NT + t] * c0 + dist[m] * c1 + wmsg * c2 + lb2;
    }
  }
  __syncthreads();

  // weighted sum over this m-chunk — f32 X (no bf16 quantization on h_agg path)
  const int f = tid & 127, half = tid >> 7;
  float xa = 0.f;
#pragma unroll 8
  for (int mm = half * 32; mm < half * 32 + 32; mm++)
    xa += lw_sh[mm] * xs[mm * PAD4 + f];
  red[half][f] = xa;
  if (tid < 64) {                       // wave-parallel sum of lw_sh
    float v = lw_sh[tid];
    v += __shfl_xor(v, 1, 64);
    v += __shfl_xor(v, 2, 64);
    v += __shfl_xor(v, 4, 64);
    v += __shfl_xor(v, 8, 64);
    v += __shfl_xor(v, 16, 64);
    v += __shfl_xor(v, 32, 64);
    if (tid == 0) red_ls = v;
  }
  __syncthreads();
  if (tid < 128) __builtin_nontemporal_store(red[0][tid] + red[1][tid],
                                             &part[(size_t)blk * 128 + tid]);
  if (tid == 128) partls[blk] = red_ls;
}

// ---------- reduce: xagg -> h_agg -> gi0   (coalesced via wih0T)
__global__ __launch_bounds__(384) void reduce_kernel(
    const float* __restrict__ part, const float* __restrict__ partls,
    const float* __restrict__ linT, const float* __restrict__ lin_b,
    const float* __restrict__ wih0T, const float* __restrict__ bih0,
    float* __restrict__ gi0)
{
  const int bt = blockIdx.x, j = threadIdx.x;
  __shared__ float sxa[128], shh[128];
  __shared__ float sls;
  if (j < 128) {
    float s = 0.f;
#pragma unroll
    for (int g2 = 0; g2 < 8; g2++)
      s += __builtin_nontemporal_load(&part[((size_t)bt * 8 + g2) * 128 + j]);
    sxa[j] = s;
  }
  if (j == 128) {
    float s = 0.f;
#pragma unroll
    for (int g2 = 0; g2 < 8; g2++) s += partls[bt * 8 + g2];
    sls = s;
  }
  __syncthreads();
  if (j < 128) {
    float hv = sls * lin_b[j];
#pragma unroll 8
    for (int f2 = 0; f2 < 128; f2++) hv += linT[f2 * 128 + j] * sxa[f2];
    shh[j] = hv;
  }
  __syncthreads();
  float gacc = bih0[j];
#pragma unroll 16
  for (int k = 0; k < 128; k++) gacc += wih0T[k * 384 + j] * shh[k];
  gi0[(size_t)bt * 384 + j] = gacc;
}

// ---------- gi for layer 1  (coalesced via wihT)
__global__ __launch_bounds__(384, 2) void gi_kernel(
    const float* __restrict__ xin, const float* __restrict__ wihT,
    const float* __restrict__ bih, float* __restrict__ gi)
{
  __shared__ __align__(16) float xr[128];
  const int bt = blockIdx.x, j = threadIdx.x;
  if (j < 128) xr[j] = xin[bt * 128 + j];
  __syncthreads();
  float a0 = 0.f, a1 = 0.f, a2 = 0.f, a3 = 0.f;
#pragma unroll 8
  for (int k = 0; k < 128; k += 4) {
    a0 += wihT[(k    ) * 384 + j] * xr[k];
    a1 += wihT[(k + 1) * 384 + j] * xr[k + 1];
    a2 += wihT[(k + 2) * 384 + j] * xr[k + 2];
    a3 += wihT[(k + 3) * 384 + j] * xr[k + 3];
  }
  gi[(size_t)bt * 384 + j] = (a0 + a1) + (a2 + a3) + bih[j];
}

// ---------- GRU recurrence: 768 threads, K-split matvec (2x64), fast gates (R0/R1 formula)
__global__ __launch_bounds__(768) void gru_layer_kernel(
    const float* __restrict__ gi, const float* __restrict__ whhT,
    const float* __restrict__ bhh, float* __restrict__ out)
{
  const int b = blockIdx.x, tid = threadIdx.x;
  const int kh = (tid >= 384) ? 1 : 0;
  const int j  = tid - kh * 384;

  __shared__ float sgi[64 * 384];   // 96 KB
  __shared__ float hs[128];
  __shared__ float pg[2][384];

  // preload gi: 6144 float4 over 768 threads = 8 rounds
  const float4* gsrc = (const float4*)(gi + (size_t)b * 64 * 384);
  float4* gdst = (float4*)sgi;
#pragma unroll
  for (int p = 0; p < 8; p++) gdst[p * 768 + tid] = gsrc[p * 768 + tid];

  // each thread holds half a whh row (K-split): wreg[k] = whh[j][kh*64+k]
  float wreg[64];
#pragma unroll
  for (int k = 0; k < 64; k++) wreg[k] = whhT[(kh * 64 + k) * 384 + j];
  const float bh = (kh == 0) ? bhh[j] : 0.f;
  if (tid < 128) hs[tid] = 0.f;
  __syncthreads();

  for (int t = 0; t < NT; t++) {
    const float4* h4 = ((const float4*)hs) + kh * 16;
    float a0 = 0.f, a1 = 0.f, a2 = 0.f, a3 = 0.f;
#pragma unroll
    for (int k = 0; k < 16; k++) {
      float4 hv = h4[k];
      a0 += wreg[4 * k]     * hv.x;
      a1 += wreg[4 * k + 1] * hv.y;
      a2 += wreg[4 * k + 2] * hv.z;
      a3 += wreg[4 * k + 3] * hv.w;
    }
    pg[kh][j] = (a0 + a1) + (a2 + a3) + bh;
    __syncthreads();
    if (tid < 128) {
      const float* gt = &sgi[t * 384];
      const float ghr = pg[0][tid]       + pg[1][tid];
      const float ghz = pg[0][tid + 128] + pg[1][tid + 128];
      const float ghn = pg[0][tid + 256] + pg[1][tid + 256];
      const float hprev = hs[tid];
      const float r = 1.f / (1.f + __expf(-(gt[tid] + ghr)));
      const float z = 1.f / (1.f + __expf(-(gt[tid + 128] + ghz)));
      float nx = gt[tid + 256] + r * ghn;
      nx = fmaxf(fminf(nx, 15.f), -15.f);
      const float e2 = __expf(2.f * nx);
      const float n = (e2 - 1.f) / (e2 + 1.f);
      const float hnew = (1.f - z) * n + z * hprev;
      hs[tid] = hnew;
      out[((size_t)b * NT + t) * 128 + tid] = hnew;
    }
    __syncthreads();
  }
}

extern "C" void kernel_launch(void* const* d_in, const int* in_sizes, int n_in,
                              void* d_out, int out_size, void* d_ws, size_t ws_size,
                              hipStream_t stream)
{
  const float* X        = (const float*)d_in[0];
  const float* C        = (const float*)d_in[1];
  const float* h_target = (const float*)d_in[2];
  const float* distance = (const float*)d_in[3];
  const float* lin_w    = (const float*)d_in[4];
  const float* lin_b    = (const float*)d_in[5];
  const float* mlp_w1   = (const float*)d_in[6];
  const float* mlp_b1   = (const float*)d_in[7];
  const float* mlp_w2   = (const float*)d_in[8];
  const float* mlp_b2   = (const float*)d_in[9];
  const float* lin2_w   = (const float*)d_in[10];
  const float* lin2_b   = (const float*)d_in[11];
  const float* wih0     = (const float*)d_in[12];
  const float* whh0     = (const float*)d_in[13];
  const float* bih0     = (const float*)d_in[14];
  const float* bhh0     = (const float*)d_in[15];
  const float* wih1     = (const float*)d_in[16];
  const float* whh1     = (const float*)d_in[17];
  const float* bih1     = (const float*)d_in[18];
  const float* bhh1     = (const float*)d_in[19];
  float* out = (float*)d_out;

  float* ws = (float*)d_ws;
  unsigned short* WxFrag = (unsigned short*)ws;      //  16384 bf16  (= 8192 floats)
  float* linT   = ws + 8192;                         //  16384
  float* u_buf  = ws + 24576;                        // 131072
  float* part   = ws + 155648;                       // 8192*128 = 1048576
  float* partls = ws + 1204224;                      //   8192
  float* gi     = ws + 1212416;                      // 393216
  float* out0   = ws + 1605632;                      // 131072
  float* W1aT   = ws + 1736704;                      //  16384
  float* wih0T  = ws + 1753088;                      //  49152
  float* whh0T  = ws + 1802240;                      //  49152
  float* wih1T  = ws + 1851392;                      //  49152
  float* whh1T  = ws + 1900544;                      //  49152
  float* ubase  = ws + 1949696;                      //    128   (total ~7.8 MB)

  setup_kernel<<<352, 256, 0, stream>>>(lin_w, mlp_w1, lin_b, mlp_b1,
      wih0, whh0, wih1, whh1,
      WxFrag, linT, ubase, wih0T, whh0T, wih1T, whh1T, W1aT);
  u_kernel<<<NB * NT, 128, 0, stream>>>(h_target, W1aT, ubase, u_buf);
  pass1_kernel<<<NB * NT * 8, 256, 0, stream>>>(X, C, distance, WxFrag, u_buf,
      mlp_w2, mlp_b2, lin2_w, lin2_b, part, partls);
  reduce_kernel<<<NB * NT, 384, 0, stream>>>(part, partls, linT, lin_b, wih0T, bih0, gi);
  gru_layer_kernel<<<NB, 768, 0, stream>>>(gi, whh0T, bhh0, out0);
  gi_kernel<<<NB * NT, 384, 0, stream>>>(out0, wih1T, bih1, gi);
  gru_layer_kernel<<<NB, 768, 0, stream>>>(gi, whh1T, bhh1, out);
}